// Round 1
// baseline (191.051 us; speedup 1.0000x reference)
//
#include <hip/hip_runtime.h>
#include <cstdint>
#include <cstddef>

#define HID 1024
#define NH 16
#define HD 64
#define BB 2
#define LL 2048
#define MM (BB*LL)       // 4096 rows
#define CHUNK 64
#define NT (LL/CHUNK)    // 32 chunks
#define BHn (BB*NH)      // 32 (b,h) chains

typedef __bf16 bf16;
typedef __attribute__((ext_vector_type(8))) __bf16 bf16x8;
typedef __attribute__((ext_vector_type(4))) float f32x4;

__device__ __forceinline__ f32x4 mfma16(bf16x8 a, bf16x8 b, f32x4 c){
  return __builtin_amdgcn_mfma_f32_16x16x32_bf16(a, b, c, 0, 0, 0);
}

__device__ __forceinline__ void gload16(const void* g, void* l){
  __builtin_amdgcn_global_load_lds(
      (const __attribute__((address_space(1))) unsigned int*)g,
      (__attribute__((address_space(3))) unsigned int*)l, 16, 0, 0);
}

// ---------------- cast fp32 -> bf16 ----------------
__global__ void cast_x_k(const float* __restrict__ src, bf16* __restrict__ dst){
  int i = blockIdx.x*256 + threadIdx.x;        // exactly MM*HID/4 threads
  float4 v = ((const float4*)src)[i];
  union { bf16 h[4]; uint2 u; } pk;
  pk.h[0]=(bf16)v.x; pk.h[1]=(bf16)v.y; pk.h[2]=(bf16)v.z; pk.h[3]=(bf16)v.w;
  *((uint2*)(dst + 4*(size_t)i)) = pk.u;
}

__global__ void cast_w_k(const float* __restrict__ w0,const float* __restrict__ w1,
                         const float* __restrict__ w2,const float* __restrict__ w3,
                         bf16* __restrict__ d0, bf16* __restrict__ d1,
                         bf16* __restrict__ d2, bf16* __restrict__ d3){
  const float* s; bf16* d;
  switch(blockIdx.y){ case 0: s=w0; d=d0; break; case 1: s=w1; d=d1; break;
                      case 2: s=w2; d=d2; break; default: s=w3; d=d3; }
  int i = blockIdx.x*256 + threadIdx.x;        // exactly HID*HID/4 threads
  float4 v = ((const float4*)s)[i];
  union { bf16 h[4]; uint2 u; } pk;
  pk.h[0]=(bf16)v.x; pk.h[1]=(bf16)v.y; pk.h[2]=(bf16)v.z; pk.h[3]=(bf16)v.w;
  *((uint2*)(d + 4*(size_t)i)) = pk.u;
}

// ---------------- GEMM: C[m,n] = sum_k A[m,k]*W[n,k] ----------------
// MODE 0: fused QKV. gridDim.x=24 (8 n-blocks per weight). elu+1 on Q,K.
//         Q stored (M,HID); K stored (M,HID) + transposed (BH,D,L); V transposed only.
// MODE 1: A=Obuf, W=Wo, fp32 store to out.
// 128x128 tile, BK=32, 4 waves (2x2 of 64x64), double-buffered LDS,
// width-16 global_load_lds staging (linear LDS layout: required).
template<int MODE>
__global__ __launch_bounds__(256) void gemm_k(
    const bf16* __restrict__ A,
    const bf16* __restrict__ W0, const bf16* __restrict__ W1, const bf16* __restrict__ W2,
    bf16* __restrict__ Qo, bf16* __restrict__ Kn, bf16* __restrict__ Kt,
    bf16* __restrict__ Vt, float* __restrict__ Outf)
{
  constexpr int BK = 32;
  __shared__ bf16 Asm[2][128*BK];
  __shared__ bf16 Bsm[2][128*BK];
  const int tid = threadIdx.x;
  const int wv = tid >> 6, lane = tid & 63;
  const int bm = blockIdx.y;
  int bn = blockIdx.x, wsel = 0;
  const bf16* W = W0;
  if (MODE==0){ wsel = bn >> 3; bn &= 7; W = (wsel==0) ? W0 : (wsel==1 ? W1 : W2); }
  const int row0 = bm*128, col0 = bn*128;
  // staging: wave w covers rows [w*32,(w+1)*32): 2 issues of 16 rows x 32 cols
  const int srow = (wv<<5) + (lane>>2), scol = (lane&3)<<3;
  const bf16* gA = A + (size_t)(row0+srow)*HID + scol;
  const bf16* gB = W + (size_t)(col0+srow)*HID + scol;
  f32x4 acc[4][4] = {};

  auto stage = [&](int buf, int kt){
    const bf16* ga = gA + kt*BK;
    const bf16* gb = gB + kt*BK;
    #pragma unroll
    for (int q=0;q<2;q++){
      gload16(ga + q*16*HID, (void*)&Asm[buf][((wv<<5)+(q<<4))*BK]);
      gload16(gb + q*16*HID, (void*)&Bsm[buf][((wv<<5)+(q<<4))*BK]);
    }
  };

  stage(0,0);
  __syncthreads();                 // drains vmcnt(0): buf0 ready
  const int wr = wv>>1, wc = wv&1;
  const int lrow = lane&15, g4 = lane>>4, lk8 = g4*8;
  int cur = 0;
  for (int kt=0; kt<HID/BK; ++kt){
    if (kt+1 < HID/BK) stage(cur^1, kt+1);
    bf16x8 af[4], bfr[4];
    #pragma unroll
    for (int i=0;i<4;i++){
      af[i]  = *(const bf16x8*)&Asm[cur][(wr*64 + i*16 + lrow)*BK + lk8];
      bfr[i] = *(const bf16x8*)&Bsm[cur][(wc*64 + i*16 + lrow)*BK + lk8];
    }
    #pragma unroll
    for (int i=0;i<4;i++)
      #pragma unroll
      for (int j=0;j<4;j++)
        acc[i][j] = mfma16(af[i], bfr[j], acc[i][j]);
    __syncthreads();               // next buffer staged + all reads done
    cur ^= 1;
  }

  #pragma unroll
  for (int i=0;i<4;i++){
    #pragma unroll
    for (int j=0;j<4;j++){
      #pragma unroll
      for (int r=0;r<4;r++){
        int m = row0 + wr*64 + i*16 + g4*4 + r;      // C/D: row=(lane>>4)*4+r
        int c = col0 + wc*64 + j*16 + lrow;          //      col=lane&15
        float v = acc[i][j][r];
        if (MODE==1){
          Outf[(size_t)m*HID + c] = v;
        } else {
          if (wsel<2) v = v>0.f ? v+1.f : __expf(v); // elu(v)+1
          bf16 bv = (bf16)v;
          if (wsel==0){
            Qo[(size_t)m*HID + c] = bv;
          } else {
            int l = m & (LL-1), b = m >> 11;
            int h = c >> 6, d = c & 63;
            size_t tix = ((size_t)((b*NH+h)*HD + d))*LL + l;
            if (wsel==1){ Kn[(size_t)m*HID + c] = bv; Kt[tix] = bv; }
            else        { Vt[tix] = bv; }
          }
        }
      }
    }
  }
}

// ---------------- pass1: per-chunk SkvT[e][d] = sum_j v_j[e] k_j[d], ksum[d] ----------------
__global__ __launch_bounds__(64) void pass1_k(const bf16* __restrict__ Kt, const bf16* __restrict__ Vt,
                                              float* __restrict__ SkvT, float* __restrict__ ksum)
{
  const int blk = blockIdx.x;                 // bh*NT + t
  const int bh = blk >> 5, t = blk & (NT-1);
  const int lane = threadIdx.x;
  const int lrow = lane&15, g4 = lane>>4, lk8 = g4*8;
  const bf16* vtb = Vt + (size_t)bh*HD*LL + t*CHUNK;
  const bf16* ktb = Kt + (size_t)bh*HD*LL + t*CHUNK;
  bf16x8 av[4][2], bk[4][2];
  #pragma unroll
  for (int i=0;i<4;i++)
    #pragma unroll
    for (int kk=0;kk<2;kk++){
      av[i][kk] = *(const bf16x8*)&vtb[(size_t)(i*16+lrow)*LL + kk*32 + lk8];
      bk[i][kk] = *(const bf16x8*)&ktb[(size_t)(i*16+lrow)*LL + kk*32 + lk8];
    }
  f32x4 acc[4][4] = {};
  #pragma unroll
  for (int i=0;i<4;i++)
    #pragma unroll
    for (int j=0;j<4;j++)
      #pragma unroll
      for (int kk=0;kk<2;kk++)
        acc[i][j] = mfma16(av[i][kk], bk[j][kk], acc[i][j]);
  float* so = SkvT + (size_t)blk*4096;
  #pragma unroll
  for (int i=0;i<4;i++)
    #pragma unroll
    for (int j=0;j<4;j++)
      #pragma unroll
      for (int r=0;r<4;r++)
        so[(i*16+g4*4+r)*64 + j*16+lrow] = acc[i][j][r];
  // ksum: lane d row-sums its Kt row over the chunk
  const bf16* krow = ktb + (size_t)lane*LL;
  float s = 0.f;
  #pragma unroll
  for (int c8=0;c8<8;c8++){
    bf16x8 v = *(const bf16x8*)&krow[c8*8];
    #pragma unroll
    for (int j=0;j<8;j++) s += (float)v[j];
  }
  ksum[(size_t)blk*64 + lane] = s;
}

// ---------------- pass2: exclusive prefix scan over chunks ----------------
__global__ __launch_bounds__(256) void pass2_k(const float* __restrict__ SkvT, const float* __restrict__ ksum,
                                               bf16* __restrict__ Sexcl, float* __restrict__ ksx)
{
  int gid = blockIdx.x*256 + threadIdx.x;
  if (gid < BHn*4096){
    int bh = gid >> 12, e = gid & 4095;
    float run = 0.f;
    size_t base = (size_t)bh*NT*4096 + e;
    for (int t=0;t<NT;t++){
      Sexcl[base + (size_t)t*4096] = (bf16)run;
      run += SkvT[base + (size_t)t*4096];
    }
  } else if (gid < BHn*4096 + BHn*64){
    int g2 = gid - BHn*4096;
    int bh = g2 >> 6, d = g2 & 63;
    float run = 0.f;
    size_t base = (size_t)bh*NT*64 + d;
    for (int t=0;t<NT;t++){
      ksx[base + (size_t)t*64] = run;
      run += ksum[base + (size_t)t*64];
    }
  }
}

// ---------------- pass3: per (b,h,chunk) output ----------------
// O = (mask(Q Kc^T) Vc + Q Sprev) / max(q·ksum_prev + rowsum(mask(Q Kc^T)), 1e-6)
__global__ __launch_bounds__(64) void pass3_k(const bf16* __restrict__ Q, const bf16* __restrict__ Kn,
                                              const bf16* __restrict__ Sexcl, const bf16* __restrict__ Vt,
                                              const float* __restrict__ ksx, bf16* __restrict__ Obuf)
{
  __shared__ bf16 P[64*72];                    // +8 pad: bank-conflict-light A-frag reads
  const int blk = blockIdx.x;
  const int bh = blk>>5, t = blk&(NT-1);
  const int b = bh>>4, h = bh&15;
  const int lane = threadIdx.x;
  const int lrow = lane&15, g4 = lane>>4, lk8 = g4*8;
  const bf16* qb = Q  + ((size_t)(b*LL + t*CHUNK))*HID + h*HD;
  const bf16* kb = Kn + ((size_t)(b*LL + t*CHUNK))*HID + h*HD;
  bf16x8 aq[4][2], bk[4][2];
  #pragma unroll
  for (int i=0;i<4;i++)
    #pragma unroll
    for (int kk=0;kk<2;kk++){
      aq[i][kk] = *(const bf16x8*)&qb[(size_t)(i*16+lrow)*HID + kk*32 + lk8];
      bk[i][kk] = *(const bf16x8*)&kb[(size_t)(i*16+lrow)*HID + kk*32 + lk8];
    }
  f32x4 sacc[4][4] = {};
  #pragma unroll
  for (int i=0;i<4;i++)
    #pragma unroll
    for (int j=0;j<4;j++)
      #pragma unroll
      for (int kk=0;kk<2;kk++)
        sacc[i][j] = mfma16(aq[i][kk], bk[j][kk], sacc[i][j]);
  // causal mask + row sums (fp32)
  float rs[4][4];
  #pragma unroll
  for (int i=0;i<4;i++)
    #pragma unroll
    for (int r=0;r<4;r++){
      int irow = i*16 + g4*4 + r;
      float p = 0.f;
      #pragma unroll
      for (int j=0;j<4;j++){
        int jcol = j*16 + lrow;
        float v = (jcol <= irow) ? sacc[i][j][r] : 0.f;
        sacc[i][j][r] = v;
        p += v;
      }
      p += __shfl_xor(p,1); p += __shfl_xor(p,2);
      p += __shfl_xor(p,4); p += __shfl_xor(p,8);
      rs[i][r] = p;
    }
  // P -> LDS (bf16) for PV A-fragments
  #pragma unroll
  for (int i=0;i<4;i++)
    #pragma unroll
    for (int j=0;j<4;j++)
      #pragma unroll
      for (int r=0;r<4;r++)
        P[(i*16+g4*4+r)*72 + j*16+lrow] = (bf16)sacc[i][j][r];
  // normalizer inter part: zA[i] = q_row(i*16+lrow) · ksum_prev
  const float* kp = ksx + (size_t)blk*64;
  float zA[4];
  #pragma unroll
  for (int i=0;i<4;i++){
    float s = 0.f;
    #pragma unroll
    for (int kk=0;kk<2;kk++){
      const float* k8 = kp + kk*32 + lk8;
      bf16x8 q = aq[i][kk];
      #pragma unroll
      for (int j=0;j<8;j++) s += (float)q[j] * k8[j];
    }
    s += __shfl_xor(s,16); s += __shfl_xor(s,32);
    zA[i] = s;
  }
  // inter: O += Q @ Sprev  (Sexcl stored as S^T[e][d], d-contiguous = Bbt operand)
  const bf16* sb = Sexcl + (size_t)blk*4096;
  f32x4 oacc[4][4] = {};
  bf16x8 bs[4][2];
  #pragma unroll
  for (int j=0;j<4;j++)
    #pragma unroll
    for (int kk=0;kk<2;kk++)
      bs[j][kk] = *(const bf16x8*)&sb[(size_t)(j*16+lrow)*64 + kk*32 + lk8];
  #pragma unroll
  for (int i=0;i<4;i++)
    #pragma unroll
    for (int j=0;j<4;j++)
      #pragma unroll
      for (int kk=0;kk<2;kk++)
        oacc[i][j] = mfma16(aq[i][kk], bs[j][kk], oacc[i][j]);
  __syncthreads();                            // P writes visible to all lanes
  // intra: O += P @ Vc  (Vt rows e, j-contiguous = Bbt operand)
  const bf16* vb = Vt + (size_t)bh*HD*LL + t*CHUNK;
  bf16x8 bv[4][2], ap[4][2];
  #pragma unroll
  for (int j=0;j<4;j++)
    #pragma unroll
    for (int kk=0;kk<2;kk++)
      bv[j][kk] = *(const bf16x8*)&vb[(size_t)(j*16+lrow)*LL + kk*32 + lk8];
  #pragma unroll
  for (int i=0;i<4;i++)
    #pragma unroll
    for (int kk=0;kk<2;kk++)
      ap[i][kk] = *(const bf16x8*)&P[(i*16+lrow)*72 + kk*32 + lk8];
  #pragma unroll
  for (int i=0;i<4;i++)
    #pragma unroll
    for (int j=0;j<4;j++)
      #pragma unroll
      for (int kk=0;kk<2;kk++)
        oacc[i][j] = mfma16(ap[i][kk], bv[j][kk], oacc[i][j]);
  // normalize + store
  bf16* ob = Obuf + ((size_t)(b*LL + t*CHUNK))*HID + h*HD;
  #pragma unroll
  for (int i=0;i<4;i++)
    #pragma unroll
    for (int r=0;r<4;r++){
      float z = __shfl(zA[i], g4*4 + r) + rs[i][r];
      z = fmaxf(z, 1e-6f);
      float inv = 1.0f/z;
      int irow = i*16 + g4*4 + r;
      #pragma unroll
      for (int j=0;j<4;j++)
        ob[(size_t)irow*HID + j*16+lrow] = (bf16)(oacc[i][j][r]*inv);
    }
}

// ---------------- launch ----------------
extern "C" void kernel_launch(void* const* d_in, const int* in_sizes, int n_in,
                              void* d_out, int out_size, void* d_ws, size_t ws_size,
                              hipStream_t stream)
{
  const float* x  = (const float*)d_in[0];
  const float* Wq = (const float*)d_in[1];
  const float* Wk = (const float*)d_in[2];
  const float* Wv = (const float*)d_in[3];
  const float* Wo = (const float*)d_in[4];
  float* out = (float*)d_out;

  char* p = (char*)d_ws;
  auto alloc = [&](size_t bytes){ void* r = (void*)p; p += (bytes + 255) & ~(size_t)255; return r; };
  bf16* xb   = (bf16*)alloc((size_t)MM*HID*2);        // 8 MB
  bf16* Wqb  = (bf16*)alloc((size_t)HID*HID*2);       // 2 MB
  bf16* Wkb  = (bf16*)alloc((size_t)HID*HID*2);
  bf16* Wvb  = (bf16*)alloc((size_t)HID*HID*2);
  bf16* Wob  = (bf16*)alloc((size_t)HID*HID*2);
  bf16* Qb   = (bf16*)alloc((size_t)MM*HID*2);        // 8 MB
  bf16* Knb  = (bf16*)alloc((size_t)MM*HID*2);
  bf16* Ktb  = (bf16*)alloc((size_t)MM*HID*2);        // (BH, D, L)
  bf16* Vtb  = (bf16*)alloc((size_t)MM*HID*2);        // (BH, D, L)
  bf16* Ob   = (bf16*)alloc((size_t)MM*HID*2);
  float* SkvT  = (float*)alloc((size_t)BHn*NT*4096*4);  // 16 MB
  bf16*  Sexcl = (bf16*) alloc((size_t)BHn*NT*4096*2);  // 8 MB
  float* ksum  = (float*)alloc((size_t)BHn*NT*64*4);
  float* ksx   = (float*)alloc((size_t)BHn*NT*64*4);
  // total ~84.5 MB of d_ws

  cast_x_k<<<dim3(MM*HID/4/256), 256, 0, stream>>>(x, xb);
  cast_w_k<<<dim3(HID*HID/4/256, 4), 256, 0, stream>>>(Wq,Wk,Wv,Wo, Wqb,Wkb,Wvb,Wob);
  gemm_k<0><<<dim3(24,32), 256, 0, stream>>>(xb, Wqb,Wkb,Wvb, Qb,Knb,Ktb,Vtb, nullptr);
  pass1_k<<<dim3(BHn*NT), 64, 0, stream>>>(Ktb, Vtb, SkvT, ksum);
  pass2_k<<<dim3((BHn*4096 + BHn*64)/256), 256, 0, stream>>>(SkvT, ksum, Sexcl, ksx);
  pass3_k<<<dim3(BHn*NT), 64, 0, stream>>>(Qb, Knb, Sexcl, Vtb, ksx, Ob);
  gemm_k<1><<<dim3(8,32), 256, 0, stream>>>(Ob, Wob,nullptr,nullptr, nullptr,nullptr,nullptr,nullptr, out);
}